// Round 12
// baseline (213.875 us; speedup 1.0000x reference)
//
#include <hip/hip_runtime.h>
#include <hip/hip_bf16.h>
#include <hip/hip_fp16.h>

// GNN layer: out = segment_sum(edge_vals * h[edge_cols], edge_rows), h = x @ W
// N=100000 nodes, E=1.6M edges, D=128.
//
// R17: R16 (packed cvt) was NEUTRAL -> gemm phase not VALU-bound. Ledger
// forces gemm_part ~60-65us (every non-bucket dispatch < 68) vs ~20us
// traffic floor. Mechanism: 1407 blocks at 4 blocks/CU (union LDS 36.9KB)
// = 1024 slots, 16 waves/CU, 1407/1024=1.37 -> 2 rounds @ 69% util.
// Fix granularity: BM 128->64 (xl 17.4KB, 1563 blocks, L halves) and
// CH 2560->1792 + NB_MAX 800 (part LDS 26.5KB) -> union 26.5KB ->
// 5 blocks/CU, 20 waves/CU, 1280 slots; 2456/1280=1.92 -> 2 rounds @ 96%.
// launch_bounds(256,5) = 102 VGPR budget (no spill squeeze; gemm peak ~65).
// bucket_accum byte-identical to R13/R16 (68.5us at its gather wall).

#define DIM 128
#define RB 128         // rows per bucket (pass-1 partition granularity)
#define NB_MAX 800     // max buckets (nb=782); scan reads guarded
#define BM 64          // gemm tile rows
#define CH 1792        // edges per pass1 block (srec 14KB -> union ~26.5KB)
#define EPT (CH / 256) // edges per thread in part (7)
#define REG_CAP 2560   // records per bucket region (mean 2048, +11 sigma)
#define DEPTH 4        // gather batches in flight per quarter (R10-proven)

typedef short s16x8 __attribute__((ext_vector_type(8)));
typedef float f32x4 __attribute__((ext_vector_type(4)));
typedef unsigned short u16;
typedef unsigned long long u64;
typedef u16 u16x4 __attribute__((ext_vector_type(4)));
typedef u16 u16x8 __attribute__((ext_vector_type(8)));

static __device__ __forceinline__ u16 f2bf(float f) {
  union { float f; unsigned u; } a; a.f = f;
  return (u16)((a.u + 0x7fffu + ((a.u >> 16) & 1u)) >> 16);
}
// packed fp32x2 -> bf16x2 via HIP intrinsic (no inline asm; RNE)
static __device__ __forceinline__ unsigned pk_bf16(float lo, float hi) {
  union { __hip_bfloat162 h; unsigned u; } c;
  c.h = __float22bfloat162_rn(make_float2(lo, hi));
  return c.u;  // low 16 = lo, high 16 = hi
}
static __device__ __forceinline__ float bf_lo(unsigned u) {
  union { unsigned u; float f; } a; a.u = u << 16; return a.f;
}
static __device__ __forceinline__ float bf_hi(unsigned u) {
  union { unsigned u; float f; } a; a.u = u & 0xffff0000u; return a.f;
}
static __device__ __forceinline__ u16 f2h(float f) {
  return __half_as_ushort(__float2half(f));
}
static __device__ __forceinline__ float h2f(u16 h) {
  return __half2float(__ushort_as_half(h));
}

// ---------------- W repack: fp32 [k][n] -> bf16 B-fragment order ----------------
__global__ __launch_bounds__(256) void repack_w_kernel(
    const float* __restrict__ W, u16* __restrict__ Wp) {
  int e = blockIdx.x * 256 + threadIdx.x;  // 0..16383
  int k = e >> 7, n = e & 127;
  Wp[((k >> 3) * 128 + n) * 8 + (k & 7)] = f2bf(W[e]);
}

// ---------------- GEMM body: h = x @ W (one 64-row tile) ----------------
static __device__ __forceinline__ void gemm_body(
    const float* __restrict__ x, const u16* __restrict__ Wp,
    u16* __restrict__ hb, int n_nodes, int m0, u16* xl) {
  const int t = threadIdx.x;

  const float4* x4 = (const float4*)x;
#pragma unroll
  for (int it = 0; it < 8; ++it) {
    int i = it * 256 + t;
    int r = i >> 5, c = i & 31;  // r in [0,64), c in [0,32)
    float4 v = make_float4(0.f, 0.f, 0.f, 0.f);
    int node = m0 + r;
    if (node < n_nodes) v = x4[(size_t)node * 32 + c];
    uint2 pk;
    pk.x = pk_bf16(v.x, v.y);
    pk.y = pk_bf16(v.z, v.w);
    *(uint2*)&xl[r * 136 + c * 4] = pk;  // byte off = r*272 + c*8, 8B-aligned
  }
  __syncthreads();

  const int w = t >> 6, l = t & 63, q = l >> 4, n15 = l & 15;

  f32x4 acc[8];
#pragma unroll
  for (int nt = 0; nt < 8; ++nt) acc[nt] = (f32x4){0.f, 0.f, 0.f, 0.f};

#pragma unroll
  for (int ks = 0; ks < 4; ++ks) {
    s16x8 a = *(const s16x8*)&xl[(w * 16 + n15) * 136 + ks * 32 + q * 8];
#pragma unroll
    for (int nt = 0; nt < 8; ++nt) {
      s16x8 b = *(const s16x8*)&Wp[(size_t)(((ks * 4 + q) * 128) + nt * 16 + n15) * 8];
      acc[nt] = __builtin_amdgcn_mfma_f32_16x16x32_bf16(a, b, acc[nt], 0, 0, 0);
    }
  }
  __syncthreads();

#pragma unroll
  for (int nt = 0; nt < 8; ++nt) {
    unsigned pA = pk_bf16(acc[nt][0], acc[nt][1]);
    unsigned pB = pk_bf16(acc[nt][2], acc[nt][3]);
    int rbase = (w * 16 + q * 4) * 136 + nt * 16 + n15;
    xl[rbase] = (u16)pA;
    xl[rbase + 136] = (u16)(pA >> 16);
    xl[rbase + 272] = (u16)pB;
    xl[rbase + 408] = (u16)(pB >> 16);
  }
  __syncthreads();

#pragma unroll
  for (int it = 0; it < 4; ++it) {
    int chunk = it * 256 + t;
    int r = chunk >> 4, c = chunk & 15;  // r in [0,64)
    int node = m0 + r;
    if (node < n_nodes)
      *(u16x8*)(hb + (size_t)node * 128 + c * 8) = *(const u16x8*)&xl[r * 136 + c * 8];
  }
}

// ---------------- part body: partition one CH-chunk of edges into row-buckets ----------------
// Scan: per-wave shfl_up inclusive scan + 4-entry cross-wave combine (5 barriers).
// NB_MAX=800 < 1024: scan lanes with b0 >= NB_MAX contribute 0 (guarded).
static __device__ __forceinline__ void part_body(
    const int* __restrict__ rows, const int* __restrict__ cols,
    const float* __restrict__ vals, int* __restrict__ gcur,
    u64* __restrict__ reg, int n_edges, int nb, int base,
    int* hist, int* ofs, int* gbase, int* lcur, int* wsum, u64* srec) {
  const int t = threadIdx.x;
  const int lane = t & 63;
  const int wid = t >> 6;

  for (int i = t; i < NB_MAX; i += 256) { hist[i] = 0; lcur[i] = 0; }
  __syncthreads();

  // load EPT edges/thread (stride-256 coalesced), LDS histogram
  int r[EPT], c[EPT];
  float v[EPT];
  bool ok[EPT];
#pragma unroll
  for (int i = 0; i < EPT; ++i) {
    int e = base + i * 256 + t;
    ok[i] = e < n_edges;
    r[i] = ok[i] ? rows[e] : 0;
    c[i] = ok[i] ? cols[e] : 0;
    v[i] = ok[i] ? vals[e] : 0.f;
    if (ok[i]) atomicAdd(&hist[r[i] >> 7], 1);
  }
  __syncthreads();

  const int b0 = t * 4;
  int h0 = 0, h1 = 0, h2 = 0, h3 = 0;
  if (b0 < NB_MAX) {
    h0 = hist[b0]; h1 = hist[b0 + 1]; h2 = hist[b0 + 2]; h3 = hist[b0 + 3];
  }
  int run = h0 + h1 + h2 + h3;

  // reserve global space per bucket (coalesced atomics; independent of scan)
  for (int b = t; b < nb; b += 256) {
    int hc = hist[b];
    gbase[b] = (hc > 0) ? atomicAdd(&gcur[b], hc) : 0;
  }

  // wave-level inclusive scan of run, then cross-wave combine (4 waves)
  int vsc = run;
#pragma unroll
  for (int off = 1; off < 64; off <<= 1) {
    int u = __shfl_up(vsc, off, 64);
    if (lane >= off) vsc += u;
  }
  if (lane == 63) wsum[wid] = vsc;
  __syncthreads();
  int wbase = 0;
#pragma unroll
  for (int ww = 0; ww < 3; ++ww)
    if (ww < wid) wbase += wsum[ww];
  int ex = wbase + vsc - run;  // exclusive prefix across 256 threads
  if (b0 < NB_MAX) {
    ofs[b0] = ex;
    ofs[b0 + 1] = ex + h0;
    ofs[b0 + 2] = ex + h0 + h1;
    ofs[b0 + 3] = ex + h0 + h1 + h2;
  }
  __syncthreads();

  // scatter records into bucket-sorted LDS order
#pragma unroll
  for (int i = 0; i < EPT; ++i) {
    if (ok[i]) {
      int bkt = r[i] >> 7;
      int pos = ofs[bkt] + atomicAdd(&lcur[bkt], 1);
      srec[pos] = ((u64)(unsigned)r[i] << 33) | ((u64)(unsigned)c[i] << 16) |
                  (u64)f2h(v[i]);
    }
  }
  __syncthreads();

  // coalesced-run write to global bucket regions
  int nvalid = n_edges - base;
  if (nvalid > CH) nvalid = CH;
  for (int i = t; i < nvalid; i += 256) {
    u64 rec = srec[i];
    int row = (int)(rec >> 33);
    int bkt = row >> 7;
    int dst = gbase[bkt] + (i - ofs[bkt]);
    if (dst < REG_CAP) reg[(size_t)bkt * REG_CAP + dst] = rec;
  }
}

// ---------------- fused GEMM + part: independent work, exact interleave ----------------
// launch_bounds(256,5): 102-VGPR budget; union LDS ~26.5KB -> 5 blocks/CU,
// 20 waves/CU, 1280 block-slots; grid 2456 -> 2 rounds @ 96% utilization.
__global__ __launch_bounds__(256, 5) void gemm_part_kernel(
    const float* __restrict__ x, const u16* __restrict__ Wp, u16* __restrict__ hb,
    const int* __restrict__ rows, const int* __restrict__ cols,
    const float* __restrict__ vals, int* __restrict__ gcur, u64* __restrict__ reg,
    int n_nodes, int n_edges, int nb, int gA, int gP) {
  __shared__ union {
    u16 xl[BM * 136];   // 17408 B (gemm)
    struct {            // 12.5KB arrays + 16B + 14KB srec = ~26.5 KB (part)
      int hist[NB_MAX];
      int ofs[NB_MAX];
      int gbase[NB_MAX];
      int lcur[NB_MAX];
      int wsum[4];
      u64 srec[CH];
    } p;
  } sh;

  // exact even interleave of gP part blocks among gA+gP total:
  // pcount(b) = floor(b*gP/G); isP iff pcount increments at b.
  const int bid = blockIdx.x;
  const long long G = gA + gP;
  const int pc0 = (int)((long long)bid * gP / G);
  const int pc1 = (int)((long long)(bid + 1) * gP / G);
  const bool isP = pc1 > pc0;
  const int id = isP ? pc0 : bid - pc0;

  if (!isP) {
    gemm_body(x, Wp, hb, n_nodes, id * BM, sh.xl);
  } else {
    part_body(rows, cols, vals, gcur, reg, n_edges, nb, id * CH,
              sh.p.hist, sh.p.ofs, sh.p.gbase, sh.p.lcur, sh.p.wsum, sh.p.srec);
  }
}

// ---------------- standalone GEMM (fallback path only) ----------------
__global__ __launch_bounds__(256) void mfma_gemm_kernel(
    const float* __restrict__ x, const u16* __restrict__ Wp,
    u16* __restrict__ hb, int n_nodes) {
  __shared__ u16 xl[BM * 136];
  gemm_body(x, Wp, hb, n_nodes, blockIdx.x * BM, xl);
}

// ---------------- pass 2: quarter-wave dwordx4 gather-accumulate (exact R10) ----------------
// One block per bucket, 1024 threads, dynamic hardware dispatch (R12 showed
// static persistent striding loses to dispatcher backfill). Quarter q of wave
// w owns local rows [w*8+2q, w*8+2q+2): contiguous row-sorted srt segment.
// Per record the quarter reads the full 256B h-row as 16x dwordx4; DEPTH=4
// batches in flight (VGPR 24, no spill). At its LLC-gather service wall
// (~410MB random 256B @ ~6 TB/s effective; 3 structural families confirm).
__global__ __launch_bounds__(1024, 6) void bucket_accum_kernel(
    const u16* __restrict__ hb, const u64* __restrict__ reg,
    const int* __restrict__ gcur, float* __restrict__ out, int n_nodes) {
  __shared__ int hist[RB];
  __shared__ int ofs[RB];
  __shared__ int lcur[RB];
  __shared__ u64 srt[REG_CAP];

  const int t = threadIdx.x;
  const int b = blockIdx.x;
  const int row0 = b * RB;

  int n_e = gcur[b];
  if (n_e > REG_CAP) n_e = REG_CAP;

  if (t < RB) { hist[t] = 0; lcur[t] = 0; }
  __syncthreads();

  // load region once (coalesced, LLC-resident), histogram by local row
  u64 rr[3];
  int rl[3];
  bool ok[3];
#pragma unroll
  for (int i = 0; i < 3; ++i) {
    int j = i * 1024 + t;
    ok[i] = j < n_e;
    rr[i] = ok[i] ? reg[(size_t)b * REG_CAP + j] : 0;
    rl[i] = (int)(rr[i] >> 33) & (RB - 1);
    if (ok[i]) atomicAdd(&hist[rl[i]], 1);
  }
  __syncthreads();

  // exclusive scan of RB=128 entries by wave 0: 2 entries/lane shuffle scan
  if (t < 64) {
    int h0 = hist[2 * t], h1 = hist[2 * t + 1];
    int s = h0 + h1;
    int v = s;
#pragma unroll
    for (int off = 1; off < 64; off <<= 1) {
      int u = __shfl_up(v, off, 64);
      if (t >= off) v += u;
    }
    int ex = v - s;  // exclusive prefix of pair-sums
    ofs[2 * t] = ex;
    ofs[2 * t + 1] = ex + h0;
  }
  __syncthreads();

  // scatter records into row-sorted LDS order
#pragma unroll
  for (int i = 0; i < 3; ++i) {
    if (ok[i]) {
      int pos = ofs[rl[i]] + atomicAdd(&lcur[rl[i]], 1);
      srt[pos] = rr[i];
    }
  }
  __syncthreads();

  const int lane = t & 63;
  const int w = t >> 6;       // wave 0..15
  const int q = lane >> 4;    // quarter 0..3
  const int li = lane & 15;   // lane-in-quarter 0..15
  const int r0 = w * 8 + q * 2;  // this quarter's first local row

  const uint4* h4 = (const uint4*)hb;  // h row = 16 uint4 (256 B)
  float4* out4 = (float4*)out;         // out row = 32 float4 (512 B)

  // zero-fill this quarter's empty rows (streaming never flushes them)
#pragma unroll
  for (int k = 0; k < 2; ++k) {
    int rli = r0 + k;
    int gr = row0 + rli;
    if (gr < n_nodes && hist[rli] == 0) {
      out4[(size_t)gr * 32 + li * 2] = make_float4(0.f, 0.f, 0.f, 0.f);
      out4[(size_t)gr * 32 + li * 2 + 1] = make_float4(0.f, 0.f, 0.f, 0.f);
    }
  }

  int qs0 = ofs[r0];
  int qs1 = ofs[r0 + 1] + hist[r0 + 1];

  if (qs1 > qs0) {
    float a0 = 0.f, a1 = 0.f, a2 = 0.f, a3 = 0.f;
    float a4 = 0.f, a5 = 0.f, a6 = 0.f, a7 = 0.f;
    int cur = (int)(srt[qs0] >> 33) & (RB - 1);

    for (int p = qs0; p < qs1; p += DEPTH) {
      // issue: DEPTH VMEM (each instruction gathers 4 records wave-wide)
      uint4 uu[DEPTH];
      unsigned mv[DEPTH];
#pragma unroll
      for (int j = 0; j < DEPTH; ++j) {
        int idx = p + j;
        idx = idx < qs1 ? idx : qs1 - 1;  // clamp: duplicate gather, masked below
        u64 rec = srt[idx];  // 4 distinct LDS addrs/wave (broadcast per quarter)
        int col = (int)((rec >> 16) & 0x1FFFF);
        mv[j] = ((unsigned)((rec >> 33) & (RB - 1)) << 16) | (unsigned)(rec & 0xFFFF);
        uu[j] = h4[(size_t)col * 16 + li];
      }
      // consume
#pragma unroll
      for (int j = 0; j < DEPTH; ++j) {
        if (p + j < qs1) {  // quarter-uniform predicate
          int lr = (int)(mv[j] >> 16);
          if (lr != cur) {  // quarter-uniform row transition: flush
            size_t o = (size_t)(row0 + cur) * 32 + li * 2;
            out4[o] = make_float4(a0, a1, a2, a3);
            out4[o + 1] = make_float4(a4, a5, a6, a7);
            a0 = a1 = a2 = a3 = a4 = a5 = a6 = a7 = 0.f;
            cur = lr;
          }
          float vv = h2f((u16)(mv[j] & 0xFFFF));
          a0 += vv * bf_lo(uu[j].x);
          a1 += vv * bf_hi(uu[j].x);
          a2 += vv * bf_lo(uu[j].y);
          a3 += vv * bf_hi(uu[j].y);
          a4 += vv * bf_lo(uu[j].z);
          a5 += vv * bf_hi(uu[j].z);
          a6 += vv * bf_lo(uu[j].w);
          a7 += vv * bf_hi(uu[j].w);
        }
      }
    }
    // final flush
    size_t o = (size_t)(row0 + cur) * 32 + li * 2;
    out4[o] = make_float4(a0, a1, a2, a3);
    out4[o + 1] = make_float4(a4, a5, a6, a7);
  }
}

// ---------------- fallback (atomic scatter on bf16 h) ----------------
__global__ __launch_bounds__(256) void scatter_kernel(
    const u16* __restrict__ hb, const float* __restrict__ vals,
    const int* __restrict__ rows, const int* __restrict__ cols,
    float* __restrict__ out, int n_edges) {
  const int lane = threadIdx.x & 63;
  const int wid = (blockIdx.x * blockDim.x + threadIdx.x) >> 6;
  const int nwaves = (gridDim.x * blockDim.x) >> 6;
  const unsigned* h32 = (const unsigned*)hb;
  for (int e = wid; e < n_edges; e += nwaves) {
    int r = rows[e];
    int c = cols[e];
    float v = vals[e];
    unsigned u = h32[(size_t)c * 64 + lane];
    float* op = out + (size_t)r * DIM + 2 * lane;
    atomicAdd(op, v * bf_lo(u));
    atomicAdd(op + 1, v * bf_hi(u));
  }
}

extern "C" void kernel_launch(void* const* d_in, const int* in_sizes, int n_in,
                              void* d_out, int out_size, void* d_ws, size_t ws_size,
                              hipStream_t stream) {
  const float* x = (const float*)d_in[0];
  const float* W = (const float*)d_in[1];
  const float* edge_vals = (const float*)d_in[2];
  const int* edge_rows = (const int*)d_in[3];
  const int* edge_cols = (const int*)d_in[4];
  float* out = (float*)d_out;

  const int n_nodes = in_sizes[0] / DIM;
  const int n_edges = in_sizes[2];
  const int nb = (n_nodes + RB - 1) / RB;

  // ws layout (16B-aligned chunks)
  char* p = (char*)d_ws;
  u16* hb = (u16*)p;   p += (((size_t)n_nodes * DIM * 2 + 15) / 16) * 16;  // 25.6 MB
  u16* Wp = (u16*)p;   p += (size_t)DIM * DIM * 2;                         // 32 KB
  int* gcur = (int*)p; p += (((size_t)nb * 4 + 15) / 16) * 16;             // ~3 KB
  u64* reg = (u64*)p;  p += (size_t)nb * REG_CAP * 8;                      // ~16 MB
  const size_t need = (size_t)(p - (char*)d_ws);

  repack_w_kernel<<<64, 256, 0, stream>>>(W, Wp);

  if (ws_size < need || nb > NB_MAX) {
    mfma_gemm_kernel<<<(n_nodes + BM - 1) / BM, 256, 0, stream>>>(x, Wp, hb, n_nodes);
    hipMemsetAsync(d_out, 0, (size_t)out_size * sizeof(float), stream);
    scatter_kernel<<<2048, 256, 0, stream>>>(hb, edge_vals, edge_rows, edge_cols,
                                             out, n_edges);
    return;
  }

  hipMemsetAsync(gcur, 0, (size_t)nb * sizeof(int), stream);

  const int gA = (n_nodes + BM - 1) / BM;
  const int gP = (n_edges + CH - 1) / CH;
  gemm_part_kernel<<<gA + gP, 256, 0, stream>>>(x, Wp, hb, edge_rows, edge_cols,
                                                edge_vals, gcur, reg, n_nodes,
                                                n_edges, nb, gA, gP);

  bucket_accum_kernel<<<nb, 1024, 0, stream>>>(hb, reg, gcur, out, n_nodes);
}

// Round 13
// 208.182 us; speedup vs baseline: 1.0273x; 1.0273x over previous
//
#include <hip/hip_runtime.h>
#include <hip/hip_bf16.h>
#include <hip/hip_fp16.h>

// GNN layer: out = segment_sum(edge_vals * h[edge_cols], edge_rows), h = x @ W
// N=100000 nodes, E=1.6M edges, D=128.
//
// R18: R17 (BM=64/CH=1792 granularity) NEUTRAL-to-worse -> slot-quantization
// theory refuted. Session ledger: non-bucket portion 141-156us INSENSITIVE to
// CH(1792-4096), BM(64/128), scan barriers(19->5), cvt ops, interleave,
// blocks/CU(3-5) — six orthogonal neutral knobs. Revert to best-verified
// R16 config (BM=128, CH=2560, 210.2us) + fold gcur zeroing into repack
// (16384 threads >= nb=782; one fewer launch; guarded for fallback).
// bucket_accum byte-identical: at its random-gather service wall
// (410MB @ ~6.1 TB/s L2-request rate = 67us; 3 structural families concur).

#define DIM 128
#define RB 128        // rows per bucket (pass-1 partition granularity)
#define NB_MAX 1024   // max buckets supported by pass1 LDS arrays
#define CH 2560       // edges per pass1 block (srec 20KB -> union ~37KB)
#define EPT (CH / 256) // edges per thread in part (10)
#define REG_CAP 2560  // records per bucket region (mean 2048, +11 sigma)
#define DEPTH 4       // gather batches in flight per quarter (R10-proven)

typedef short s16x8 __attribute__((ext_vector_type(8)));
typedef float f32x4 __attribute__((ext_vector_type(4)));
typedef unsigned short u16;
typedef unsigned long long u64;
typedef u16 u16x4 __attribute__((ext_vector_type(4)));
typedef u16 u16x8 __attribute__((ext_vector_type(8)));

static __device__ __forceinline__ u16 f2bf(float f) {
  union { float f; unsigned u; } a; a.f = f;
  return (u16)((a.u + 0x7fffu + ((a.u >> 16) & 1u)) >> 16);
}
// packed fp32x2 -> bf16x2 via HIP intrinsic (no inline asm; RNE)
static __device__ __forceinline__ unsigned pk_bf16(float lo, float hi) {
  union { __hip_bfloat162 h; unsigned u; } c;
  c.h = __float22bfloat162_rn(make_float2(lo, hi));
  return c.u;  // low 16 = lo, high 16 = hi
}
static __device__ __forceinline__ float bf_lo(unsigned u) {
  union { unsigned u; float f; } a; a.u = u << 16; return a.f;
}
static __device__ __forceinline__ float bf_hi(unsigned u) {
  union { unsigned u; float f; } a; a.u = u & 0xffff0000u; return a.f;
}
static __device__ __forceinline__ u16 f2h(float f) {
  return __half_as_ushort(__float2half(f));
}
static __device__ __forceinline__ float h2f(u16 h) {
  return __half2float(__ushort_as_half(h));
}

// ---------------- W repack (+ gcur zero): fp32 [k][n] -> bf16 B-fragment order ----------------
__global__ __launch_bounds__(256) void repack_w_kernel(
    const float* __restrict__ W, u16* __restrict__ Wp,
    int* __restrict__ gcur, int nzero) {
  int e = blockIdx.x * 256 + threadIdx.x;  // 0..16383
  int k = e >> 7, n = e & 127;
  Wp[((k >> 3) * 128 + n) * 8 + (k & 7)] = f2bf(W[e]);
  if (e < nzero) gcur[e] = 0;  // nzero=0 on fallback path (gcur may be invalid)
}

// ---------------- GEMM body: h = x @ W (one 128-row tile) ----------------
static __device__ __forceinline__ void gemm_body(
    const float* __restrict__ x, const u16* __restrict__ Wp,
    u16* __restrict__ hb, int n_nodes, int m0, u16* xl) {
  const int t = threadIdx.x;

  const float4* x4 = (const float4*)x;
#pragma unroll
  for (int it = 0; it < 16; ++it) {
    int i = it * 256 + t;
    int r = i >> 5, c = i & 31;
    float4 v = make_float4(0.f, 0.f, 0.f, 0.f);
    int node = m0 + r;
    if (node < n_nodes) v = x4[(size_t)node * 32 + c];
    uint2 pk;
    pk.x = pk_bf16(v.x, v.y);
    pk.y = pk_bf16(v.z, v.w);
    *(uint2*)&xl[r * 136 + c * 4] = pk;  // byte off = r*272 + c*8, 8B-aligned
  }
  __syncthreads();

  const int w = t >> 6, l = t & 63, q = l >> 4, n15 = l & 15;

  f32x4 acc[2][8];
#pragma unroll
  for (int mt = 0; mt < 2; ++mt)
#pragma unroll
    for (int nt = 0; nt < 8; ++nt) acc[mt][nt] = (f32x4){0.f, 0.f, 0.f, 0.f};

#pragma unroll
  for (int ks = 0; ks < 4; ++ks) {
    s16x8 a0 = *(const s16x8*)&xl[(w * 32 + n15) * 136 + ks * 32 + q * 8];
    s16x8 a1 = *(const s16x8*)&xl[(w * 32 + 16 + n15) * 136 + ks * 32 + q * 8];
#pragma unroll
    for (int nt = 0; nt < 8; ++nt) {
      s16x8 b = *(const s16x8*)&Wp[(size_t)(((ks * 4 + q) * 128) + nt * 16 + n15) * 8];
      acc[0][nt] = __builtin_amdgcn_mfma_f32_16x16x32_bf16(a0, b, acc[0][nt], 0, 0, 0);
      acc[1][nt] = __builtin_amdgcn_mfma_f32_16x16x32_bf16(a1, b, acc[1][nt], 0, 0, 0);
    }
  }
  __syncthreads();

#pragma unroll
  for (int mt = 0; mt < 2; ++mt)
#pragma unroll
    for (int nt = 0; nt < 8; ++nt) {
      unsigned pA = pk_bf16(acc[mt][nt][0], acc[mt][nt][1]);
      unsigned pB = pk_bf16(acc[mt][nt][2], acc[mt][nt][3]);
      int rbase = (w * 32 + mt * 16 + q * 4) * 136 + nt * 16 + n15;
      xl[rbase] = (u16)pA;
      xl[rbase + 136] = (u16)(pA >> 16);
      xl[rbase + 272] = (u16)pB;
      xl[rbase + 408] = (u16)(pB >> 16);
    }
  __syncthreads();

#pragma unroll
  for (int it = 0; it < 8; ++it) {
    int chunk = it * 256 + t;
    int r = chunk >> 4, c = chunk & 15;
    int node = m0 + r;
    if (node < n_nodes)
      *(u16x8*)(hb + (size_t)node * 128 + c * 8) = *(const u16x8*)&xl[r * 136 + c * 8];
  }
}

// ---------------- part body: partition one CH-chunk of edges into row-buckets ----------------
// Scan: per-wave shfl_up inclusive scan + 4-entry cross-wave combine (5 barriers).
static __device__ __forceinline__ void part_body(
    const int* __restrict__ rows, const int* __restrict__ cols,
    const float* __restrict__ vals, int* __restrict__ gcur,
    u64* __restrict__ reg, int n_edges, int nb, int base,
    int* hist, int* ofs, int* gbase, int* lcur, int* wsum, u64* srec) {
  const int t = threadIdx.x;
  const int lane = t & 63;
  const int wid = t >> 6;

  for (int i = t; i < NB_MAX; i += 256) { hist[i] = 0; lcur[i] = 0; }
  __syncthreads();

  // load EPT edges/thread (stride-256 coalesced), LDS histogram
  int r[EPT], c[EPT];
  float v[EPT];
  bool ok[EPT];
#pragma unroll
  for (int i = 0; i < EPT; ++i) {
    int e = base + i * 256 + t;
    ok[i] = e < n_edges;
    r[i] = ok[i] ? rows[e] : 0;
    c[i] = ok[i] ? cols[e] : 0;
    v[i] = ok[i] ? vals[e] : 0.f;
    if (ok[i]) atomicAdd(&hist[r[i] >> 7], 1);
  }
  __syncthreads();

  const int b0 = t * 4;
  int h0 = hist[b0], h1 = hist[b0 + 1], h2 = hist[b0 + 2], h3 = hist[b0 + 3];
  int run = h0 + h1 + h2 + h3;

  // reserve global space per bucket (coalesced atomics; independent of scan)
  for (int b = t; b < nb; b += 256) {
    int hc = hist[b];
    gbase[b] = (hc > 0) ? atomicAdd(&gcur[b], hc) : 0;
  }

  // wave-level inclusive scan of run, then cross-wave combine (4 waves)
  int vsc = run;
#pragma unroll
  for (int off = 1; off < 64; off <<= 1) {
    int u = __shfl_up(vsc, off, 64);
    if (lane >= off) vsc += u;
  }
  if (lane == 63) wsum[wid] = vsc;
  __syncthreads();
  int wbase = 0;
#pragma unroll
  for (int ww = 0; ww < 3; ++ww)
    if (ww < wid) wbase += wsum[ww];
  int ex = wbase + vsc - run;  // exclusive prefix across 256 threads
  ofs[b0] = ex;
  ofs[b0 + 1] = ex + h0;
  ofs[b0 + 2] = ex + h0 + h1;
  ofs[b0 + 3] = ex + h0 + h1 + h2;
  __syncthreads();

  // scatter records into bucket-sorted LDS order
#pragma unroll
  for (int i = 0; i < EPT; ++i) {
    if (ok[i]) {
      int bkt = r[i] >> 7;
      int pos = ofs[bkt] + atomicAdd(&lcur[bkt], 1);
      srec[pos] = ((u64)(unsigned)r[i] << 33) | ((u64)(unsigned)c[i] << 16) |
                  (u64)f2h(v[i]);
    }
  }
  __syncthreads();

  // coalesced-run write to global bucket regions
  int nvalid = n_edges - base;
  if (nvalid > CH) nvalid = CH;
  for (int i = t; i < nvalid; i += 256) {
    u64 rec = srec[i];
    int row = (int)(rec >> 33);
    int bkt = row >> 7;
    int dst = gbase[bkt] + (i - ofs[bkt]);
    if (dst < REG_CAP) reg[(size_t)bkt * REG_CAP + dst] = rec;
  }
}

// ---------------- fused GEMM + part: independent work, exact interleave ----------------
__global__ __launch_bounds__(256) void gemm_part_kernel(
    const float* __restrict__ x, const u16* __restrict__ Wp, u16* __restrict__ hb,
    const int* __restrict__ rows, const int* __restrict__ cols,
    const float* __restrict__ vals, int* __restrict__ gcur, u64* __restrict__ reg,
    int n_nodes, int n_edges, int nb, int gA, int gP) {
  __shared__ union {
    u16 xl[128 * 136];  // 34816 B (gemm)
    struct {            // 16KB arrays + 16B + 20KB srec = ~36.9 KB (part)
      int hist[NB_MAX];
      int ofs[NB_MAX];
      int gbase[NB_MAX];
      int lcur[NB_MAX];
      int wsum[4];
      u64 srec[CH];
    } p;
  } sh;

  // exact even interleave of gP part blocks among gA+gP total:
  // pcount(b) = floor(b*gP/G); isP iff pcount increments at b.
  const int bid = blockIdx.x;
  const long long G = gA + gP;
  const int pc0 = (int)((long long)bid * gP / G);
  const int pc1 = (int)((long long)(bid + 1) * gP / G);
  const bool isP = pc1 > pc0;
  const int id = isP ? pc0 : bid - pc0;

  if (!isP) {
    gemm_body(x, Wp, hb, n_nodes, id * 128, sh.xl);
  } else {
    part_body(rows, cols, vals, gcur, reg, n_edges, nb, id * CH,
              sh.p.hist, sh.p.ofs, sh.p.gbase, sh.p.lcur, sh.p.wsum, sh.p.srec);
  }
}

// ---------------- standalone GEMM (fallback path only) ----------------
__global__ __launch_bounds__(256) void mfma_gemm_kernel(
    const float* __restrict__ x, const u16* __restrict__ Wp,
    u16* __restrict__ hb, int n_nodes) {
  __shared__ u16 xl[128 * 136];
  gemm_body(x, Wp, hb, n_nodes, blockIdx.x * 128, xl);
}

// ---------------- pass 2: quarter-wave dwordx4 gather-accumulate (exact R10) ----------------
// One block per bucket, 1024 threads, dynamic hardware dispatch (R12 showed
// static persistent striding loses to dispatcher backfill). Quarter q of wave
// w owns local rows [w*8+2q, w*8+2q+2): contiguous row-sorted srt segment.
// Per record the quarter reads the full 256B h-row as 16x dwordx4; DEPTH=4
// batches in flight (VGPR 24, no spill). At its LLC-gather service wall
// (~410MB random 256B @ ~6.1 TB/s request rate; 3 structural families concur).
__global__ __launch_bounds__(1024, 6) void bucket_accum_kernel(
    const u16* __restrict__ hb, const u64* __restrict__ reg,
    const int* __restrict__ gcur, float* __restrict__ out, int n_nodes) {
  __shared__ int hist[RB];
  __shared__ int ofs[RB];
  __shared__ int lcur[RB];
  __shared__ u64 srt[REG_CAP];

  const int t = threadIdx.x;
  const int b = blockIdx.x;
  const int row0 = b * RB;

  int n_e = gcur[b];
  if (n_e > REG_CAP) n_e = REG_CAP;

  if (t < RB) { hist[t] = 0; lcur[t] = 0; }
  __syncthreads();

  // load region once (coalesced, LLC-resident), histogram by local row
  u64 rr[3];
  int rl[3];
  bool ok[3];
#pragma unroll
  for (int i = 0; i < 3; ++i) {
    int j = i * 1024 + t;
    ok[i] = j < n_e;
    rr[i] = ok[i] ? reg[(size_t)b * REG_CAP + j] : 0;
    rl[i] = (int)(rr[i] >> 33) & (RB - 1);
    if (ok[i]) atomicAdd(&hist[rl[i]], 1);
  }
  __syncthreads();

  // exclusive scan of RB=128 entries by wave 0: 2 entries/lane shuffle scan
  if (t < 64) {
    int h0 = hist[2 * t], h1 = hist[2 * t + 1];
    int s = h0 + h1;
    int v = s;
#pragma unroll
    for (int off = 1; off < 64; off <<= 1) {
      int u = __shfl_up(v, off, 64);
      if (t >= off) v += u;
    }
    int ex = v - s;  // exclusive prefix of pair-sums
    ofs[2 * t] = ex;
    ofs[2 * t + 1] = ex + h0;
  }
  __syncthreads();

  // scatter records into row-sorted LDS order
#pragma unroll
  for (int i = 0; i < 3; ++i) {
    if (ok[i]) {
      int pos = ofs[rl[i]] + atomicAdd(&lcur[rl[i]], 1);
      srt[pos] = rr[i];
    }
  }
  __syncthreads();

  const int lane = t & 63;
  const int w = t >> 6;       // wave 0..15
  const int q = lane >> 4;    // quarter 0..3
  const int li = lane & 15;   // lane-in-quarter 0..15
  const int r0 = w * 8 + q * 2;  // this quarter's first local row

  const uint4* h4 = (const uint4*)hb;  // h row = 16 uint4 (256 B)
  float4* out4 = (float4*)out;         // out row = 32 float4 (512 B)

  // zero-fill this quarter's empty rows (streaming never flushes them)
#pragma unroll
  for (int k = 0; k < 2; ++k) {
    int rli = r0 + k;
    int gr = row0 + rli;
    if (gr < n_nodes && hist[rli] == 0) {
      out4[(size_t)gr * 32 + li * 2] = make_float4(0.f, 0.f, 0.f, 0.f);
      out4[(size_t)gr * 32 + li * 2 + 1] = make_float4(0.f, 0.f, 0.f, 0.f);
    }
  }

  int qs0 = ofs[r0];
  int qs1 = ofs[r0 + 1] + hist[r0 + 1];

  if (qs1 > qs0) {
    float a0 = 0.f, a1 = 0.f, a2 = 0.f, a3 = 0.f;
    float a4 = 0.f, a5 = 0.f, a6 = 0.f, a7 = 0.f;
    int cur = (int)(srt[qs0] >> 33) & (RB - 1);

    for (int p = qs0; p < qs1; p += DEPTH) {
      // issue: DEPTH VMEM (each instruction gathers 4 records wave-wide)
      uint4 uu[DEPTH];
      unsigned mv[DEPTH];
#pragma unroll
      for (int j = 0; j < DEPTH; ++j) {
        int idx = p + j;
        idx = idx < qs1 ? idx : qs1 - 1;  // clamp: duplicate gather, masked below
        u64 rec = srt[idx];  // 4 distinct LDS addrs/wave (broadcast per quarter)
        int col = (int)((rec >> 16) & 0x1FFFF);
        mv[j] = ((unsigned)((rec >> 33) & (RB - 1)) << 16) | (unsigned)(rec & 0xFFFF);
        uu[j] = h4[(size_t)col * 16 + li];
      }
      // consume
#pragma unroll
      for (int j = 0; j < DEPTH; ++j) {
        if (p + j < qs1) {  // quarter-uniform predicate
          int lr = (int)(mv[j] >> 16);
          if (lr != cur) {  // quarter-uniform row transition: flush
            size_t o = (size_t)(row0 + cur) * 32 + li * 2;
            out4[o] = make_float4(a0, a1, a2, a3);
            out4[o + 1] = make_float4(a4, a5, a6, a7);
            a0 = a1 = a2 = a3 = a4 = a5 = a6 = a7 = 0.f;
            cur = lr;
          }
          float vv = h2f((u16)(mv[j] & 0xFFFF));
          a0 += vv * bf_lo(uu[j].x);
          a1 += vv * bf_hi(uu[j].x);
          a2 += vv * bf_lo(uu[j].y);
          a3 += vv * bf_hi(uu[j].y);
          a4 += vv * bf_lo(uu[j].z);
          a5 += vv * bf_hi(uu[j].z);
          a6 += vv * bf_lo(uu[j].w);
          a7 += vv * bf_hi(uu[j].w);
        }
      }
    }
    // final flush
    size_t o = (size_t)(row0 + cur) * 32 + li * 2;
    out4[o] = make_float4(a0, a1, a2, a3);
    out4[o + 1] = make_float4(a4, a5, a6, a7);
  }
}

// ---------------- fallback (atomic scatter on bf16 h) ----------------
__global__ __launch_bounds__(256) void scatter_kernel(
    const u16* __restrict__ hb, const float* __restrict__ vals,
    const int* __restrict__ rows, const int* __restrict__ cols,
    float* __restrict__ out, int n_edges) {
  const int lane = threadIdx.x & 63;
  const int wid = (blockIdx.x * blockDim.x + threadIdx.x) >> 6;
  const int nwaves = (gridDim.x * blockDim.x) >> 6;
  const unsigned* h32 = (const unsigned*)hb;
  for (int e = wid; e < n_edges; e += nwaves) {
    int r = rows[e];
    int c = cols[e];
    float v = vals[e];
    unsigned u = h32[(size_t)c * 64 + lane];
    float* op = out + (size_t)r * DIM + 2 * lane;
    atomicAdd(op, v * bf_lo(u));
    atomicAdd(op + 1, v * bf_hi(u));
  }
}

extern "C" void kernel_launch(void* const* d_in, const int* in_sizes, int n_in,
                              void* d_out, int out_size, void* d_ws, size_t ws_size,
                              hipStream_t stream) {
  const float* x = (const float*)d_in[0];
  const float* W = (const float*)d_in[1];
  const float* edge_vals = (const float*)d_in[2];
  const int* edge_rows = (const int*)d_in[3];
  const int* edge_cols = (const int*)d_in[4];
  float* out = (float*)d_out;

  const int n_nodes = in_sizes[0] / DIM;
  const int n_edges = in_sizes[2];
  const int nb = (n_nodes + RB - 1) / RB;

  // ws layout (16B-aligned chunks)
  char* p = (char*)d_ws;
  u16* hb = (u16*)p;   p += (((size_t)n_nodes * DIM * 2 + 15) / 16) * 16;  // 25.6 MB
  u16* Wp = (u16*)p;   p += (size_t)DIM * DIM * 2;                         // 32 KB
  int* gcur = (int*)p; p += (((size_t)nb * 4 + 15) / 16) * 16;             // ~3 KB
  u64* reg = (u64*)p;  p += (size_t)nb * REG_CAP * 8;                      // ~16 MB
  const size_t need = (size_t)(p - (char*)d_ws);

  const bool fast = (ws_size >= need) && (nb <= NB_MAX);

  // repack W; also zeroes gcur[0..nb) on the fast path (one fewer launch)
  repack_w_kernel<<<64, 256, 0, stream>>>(W, Wp, gcur, fast ? nb : 0);

  if (!fast) {
    mfma_gemm_kernel<<<(n_nodes + 127) / 128, 256, 0, stream>>>(x, Wp, hb, n_nodes);
    hipMemsetAsync(d_out, 0, (size_t)out_size * sizeof(float), stream);
    scatter_kernel<<<2048, 256, 0, stream>>>(hb, edge_vals, edge_rows, edge_cols,
                                             out, n_edges);
    return;
  }

  const int gA = (n_nodes + 127) / 128;
  const int gP = (n_edges + CH - 1) / CH;
  gemm_part_kernel<<<gA + gP, 256, 0, stream>>>(x, Wp, hb, edge_rows, edge_cols,
                                                edge_vals, gcur, reg, n_nodes,
                                                n_edges, nb, gA, gP);

  bucket_accum_kernel<<<nb, 1024, 0, stream>>>(hb, reg, gcur, out, n_nodes);
}